// Round 20
// baseline (105.438 us; speedup 1.0000x reference)
//
#include <hip/hip_runtime.h>
#include <hip/hip_fp16.h>
#include <math.h>

// AdjustNet: B=32, L=512, C=256, N=16 — R17/R19 config + K3 A-direct:
// drop K3's At LDS staging (A-fragments are contiguous 16B chunks of L2-hot
// qbuf rows, read direct from global) -> pool 34.8KB -> 32KB -> 5 blocks/CU.
// Barrier structure unchanged (Bt staging identical) — no new race surface.
//  K0: transpose+cast weights
//  K12: fused sample_layer (BK=64, reg-prefetched) — R19 exact
//  K3: adjust_layer, 32KB LDS, 5 blocks/CU, A+w4T+b3 direct from L2
//  K4: gather-blend, XCD-local batches, NT stores — R12 exact

typedef _Float16 f16;
typedef _Float16 f16x8 __attribute__((ext_vector_type(8)));
typedef float f32x4 __attribute__((ext_vector_type(4)));

#define ZERO4 f32x4{0.f, 0.f, 0.f, 0.f}

__device__ __forceinline__ float gelu_exact(float v) {
  return 0.5f * v * (1.0f + erff(v * 0.70710678118654752f));
}

// ---------------------------------------------------------------- K0 (weights only)
__global__ __launch_bounds__(256) void k0_prep(
    const float* __restrict__ w1, const float* __restrict__ w2,
    const float* __restrict__ w3, const float* __restrict__ w4,
    f16* __restrict__ w1T, f16* __restrict__ w2T,
    f16* __restrict__ w3T, f16* __restrict__ w4T) {
  __shared__ f16 tile[64][80];
  int blk = blockIdx.x;
  const int tid = threadIdx.x;
  const float* in; f16* out; int R, Cc, tr, tc;
  if (blk < 16)      { in = w1; out = w1T; R = 512; Cc = 128; tr = blk >> 1; tc = blk & 1; }
  else if (blk < 32) { blk -= 16; in = w2; out = w2T; R = 128; Cc = 512; tr = blk >> 3; tc = blk & 7; }
  else if (blk < 48) { blk -= 32; in = w3; out = w3T; R = 256; Cc = 256; tr = blk >> 2; tc = blk & 3; }
  else               { blk -= 48; in = w4; out = w4T; R = 256; Cc = 32;  tr = blk;      tc = 0; }
  const int r0 = tr * 64, c0 = tc * 64;
  for (int id = tid; id < 4096; id += 256) {
    int rr = id >> 6, cc = id & 63;
    if (c0 + cc < Cc) tile[cc][rr] = (f16)in[(r0 + rr) * Cc + c0 + cc];
  }
  __syncthreads();
  for (int id = tid; id < 512; id += 256) {
    int cc = id >> 3, ch = id & 7;
    if (c0 + cc < Cc)
      *(f16x8*)(out + (c0 + cc) * R + r0 + ch * 8) = *(f16x8*)&tile[cc][ch * 8];
  }
}

// ---------------------------------------------------------------- K12 (R19 exact)
// grid 512: b = blk>>4, c0 = (blk&15)*16.
__global__ __launch_bounds__(256) void k12_sample(
    const float* __restrict__ query, const f16* __restrict__ w1T,
    const f16* __restrict__ w2T,
    const float* __restrict__ b1, const float* __restrict__ g1,
    const float* __restrict__ bt1, const float* __restrict__ b2,
    f16* __restrict__ qout) {
  __shared__ char pool[38912];
  const int tid = threadIdx.x;
  const int b = blockIdx.x >> 4;
  const int c0 = (blockIdx.x & 15) << 4;
  const int lane = tid & 63, w = tid >> 6;
  const int mrow = lane & 15, kg = lane >> 4;
  char* At = pool;
  char* Bt = pool + 2048;
  char* t1s = pool + 32768;
  float* sb2 = (float*)(pool + 36864);

  sb2[tid] = b2[tid];
  sb2[tid + 256] = b2[tid + 256];

  const int qll = tid >> 4, qcc = tid & 15;
  const int wrj = tid >> 3, wch = tid & 7;
  float qv[4]; f16x8 wv[4];
#pragma unroll
  for (int it = 0; it < 4; ++it) {
    qv[it] = query[(((b << 9) + qll + it * 16) << 8) + c0 + qcc];
    wv[it] = *(const f16x8*)(w1T + (wrj + it * 32) * 512 + wch * 8);
  }

  f32x4 acc[2] = {ZERO4, ZERO4};
  for (int s = 0; s < 8; ++s) {
#pragma unroll
    for (int it = 0; it < 4; ++it) {
      int ll = qll + it * 16;
      *(f16*)(At + qcc * 128 + ((2 * ll) ^ ((qcc & 7) << 4))) = (f16)qv[it];
    }
#pragma unroll
    for (int it = 0; it < 4; ++it) {
      int rj = wrj + it * 32;
      *(f16x8*)(Bt + rj * 128 + ((wch * 16) ^ ((rj & 7) << 4))) = wv[it];
    }
    __syncthreads();
    if (s < 7) {
      const int k0n = (s + 1) << 6;
#pragma unroll
      for (int it = 0; it < 4; ++it) {
        qv[it] = query[(((b << 9) + k0n + qll + it * 16) << 8) + c0 + qcc];
        wv[it] = *(const f16x8*)(w1T + (wrj + it * 32) * 512 + k0n + wch * 8);
      }
    }
#pragma unroll
    for (int kk = 0; kk < 2; ++kk) {
      f16x8 a = *(const f16x8*)(At + mrow * 128 + (((kk << 6) + (kg << 4)) ^ ((mrow & 7) << 4)));
#pragma unroll
      for (int nf = 0; nf < 2; ++nf) {
        int rn = w * 32 + nf * 16 + mrow;
        f16x8 bfr = *(const f16x8*)(Bt + rn * 128 + (((kk << 6) + (kg << 4)) ^ ((rn & 7) << 4)));
        acc[nf] = __builtin_amdgcn_mfma_f32_16x16x32_f16(a, bfr, acc[nf], 0, 0, 0);
      }
    }
    __syncthreads();
  }

  f16x8 av[8];
#pragma unroll
  for (int it = 0; it < 8; ++it)
    av[it] = *(const f16x8*)(w2T + ((tid >> 4) + it * 16) * 128 + (tid & 15) * 8);

  float (*hs)[132] = (float(*)[132])pool;
#pragma unroll
  for (int nf = 0; nf < 2; ++nf)
#pragma unroll
    for (int i = 0; i < 4; ++i)
      hs[kg * 4 + i][w * 32 + nf * 16 + mrow] = acc[nf][i];
  __syncthreads();
  {
    const int r = tid >> 4, g = tid & 15;
    float s1 = 0.f, s2 = 0.f, vals[8];
#pragma unroll
    for (int jj = 0; jj < 8; ++jj) {
      int j = g * 8 + jj;
      float v = hs[r][j] + b1[j];
      vals[jj] = v; s1 += v; s2 += v * v;
    }
#pragma unroll
    for (int m = 1; m < 16; m <<= 1) { s1 += __shfl_xor(s1, m, 64); s2 += __shfl_xor(s2, m, 64); }
    const float mean = s1 * (1.f / 128.f);
    float var = fmaxf(s2 * (1.f / 128.f) - mean * mean, 0.f);
    const float rstd = rsqrtf(var + 1e-12f);
    f16 ov[8];
#pragma unroll
    for (int jj = 0; jj < 8; ++jj) {
      int j = g * 8 + jj;
      float v = (vals[jj] - mean) * rstd * g1[j] + bt1[j];
      ov[jj] = (f16)gelu_exact(v);
    }
    __syncthreads();
    *(f16x8*)(t1s + r * 256 + ((g * 16) ^ ((r & 7) << 4))) = *(f16x8*)ov;
  }
  __syncthreads();

  char* At2 = pool;
  const int ar2 = tid >> 4, ac2 = tid & 15;
  for (int lc = 0; lc < 4; ++lc) {
#pragma unroll
    for (int it = 0; it < 8; ++it) {
      int r = ar2 + it * 16;
      *(f16x8*)(At2 + r * 256 + ((ac2 * 16) ^ ((r & 7) << 4))) = av[it];
    }
    __syncthreads();
    if (lc < 3) {
#pragma unroll
      for (int it = 0; it < 8; ++it)
        av[it] = *(const f16x8*)(w2T + ((lc + 1) * 128 + ar2 + it * 16) * 128 + ac2 * 8);
    }
    f32x4 acc2[2] = {ZERO4, ZERO4};
#pragma unroll
    for (int ks = 0; ks < 4; ++ks) {
      f16x8 bfr = *(const f16x8*)(t1s + mrow * 256 + (((ks << 6) + (kg << 4)) ^ ((mrow & 7) << 4)));
#pragma unroll
      for (int mf = 0; mf < 2; ++mf) {
        int rm = w * 32 + mf * 16 + mrow;
        f16x8 a = *(const f16x8*)(At2 + rm * 256 + (((ks << 6) + (kg << 4)) ^ ((rm & 7) << 4)));
        acc2[mf] = __builtin_amdgcn_mfma_f32_16x16x32_f16(a, bfr, acc2[mf], 0, 0, 0);
      }
    }
#pragma unroll
    for (int mf = 0; mf < 2; ++mf)
#pragma unroll
      for (int i = 0; i < 4; ++i) {
        int l = lc * 128 + w * 32 + mf * 16 + kg * 4 + i;
        qout[((b << 9) + l) * 256 + c0 + mrow] = (f16)(acc2[mf][i] + sb2[l]);
      }
    __syncthreads();
  }
}

// ---------------------------------------------------------------- K3 (32KB LDS, 5 blocks/CU)
// grid 1024: b=blk>>5, l0=(blk&31)*16. A-fragments + w4T + b3 direct from L2.
__global__ __launch_bounds__(256) void k3_adjust(
    const f16* __restrict__ qbuf, const f16* __restrict__ w3T,
    const float* __restrict__ b3, const float* __restrict__ g3,
    const float* __restrict__ bt3, const f16* __restrict__ w4T,
    const float* __restrict__ b4, const float* __restrict__ offset,
    float* __restrict__ off_out, float* __restrict__ pos_out) {
  __shared__ __align__(16) char pool[32768];
  // phase1: Bt [128 rows x 128B] @0 (16KB used per k-step; rows r=0..127 over 32KB? see map)
  // NOTE: Bt rows span 256 w3T rows in 8 it-steps of 32 -> 256 rows x 128B = 32KB exactly.
  // phase2 overlay: hs [16][264] f32 @0 (16.9KB); ts @17408 (8KB)
  const int tid = threadIdx.x;
  const int b = blockIdx.x >> 5;
  const int l0 = (blockIdx.x & 31) << 4;
  const int lane = tid & 63, w = tid >> 6;
  const int mrow = lane & 15, kg = lane >> 4;
  char* Bt = pool;

  const int sr = tid >> 3, sc = tid & 7;
  f16x8 bq[8];
#pragma unroll
  for (int it = 0; it < 8; ++it)
    bq[it] = *(const f16x8*)(w3T + (sr + it * 32) * 256 + sc * 8);

  // A row pointer for this lane (row l0+mrow of qbuf, full K)
  const f16* arow = qbuf + ((b << 9) + l0 + mrow) * 256;

  f32x4 acc[4] = {ZERO4, ZERO4, ZERO4, ZERO4};
  for (int s = 0; s < 4; ++s) {
#pragma unroll
    for (int it = 0; it < 8; ++it) {
      int r = sr + it * 32;
      *(f16x8*)(Bt + r * 128 + ((sc * 16) ^ ((r & 7) << 4))) = bq[it];
    }
    __syncthreads();
    if (s < 3) {
      const int k0n = (s + 1) << 6;
#pragma unroll
      for (int it = 0; it < 8; ++it)
        bq[it] = *(const f16x8*)(w3T + (sr + it * 32) * 256 + k0n + sc * 8);
    }
#pragma unroll
    for (int kk = 0; kk < 2; ++kk) {
      f16x8 a = *(const f16x8*)(arow + (s << 6) + (kk << 5) + (kg << 3));
#pragma unroll
      for (int nf = 0; nf < 4; ++nf) {
        int rn = w * 64 + nf * 16 + mrow;
        f16x8 bfr = *(const f16x8*)(Bt + rn * 128 + (((kk << 6) + (kg << 4)) ^ ((rn & 7) << 4)));
        acc[nf] = __builtin_amdgcn_mfma_f32_16x16x32_f16(a, bfr, acc[nf], 0, 0, 0);
      }
    }
    __syncthreads();
  }
  float (*hs)[264] = (float(*)[264])pool;
  char* ts = pool + 17408;
#pragma unroll
  for (int nf = 0; nf < 4; ++nf) {
    int col = w * 64 + nf * 16 + mrow;
    float bias = b3[col];
#pragma unroll
    for (int i = 0; i < 4; ++i)
      hs[kg * 4 + i][col] = acc[nf][i] + bias;
  }
  __syncthreads();
  {
    const int r = tid >> 4, g = tid & 15;
    float s1 = 0.f, s2 = 0.f, vals[16];
#pragma unroll
    for (int jj = 0; jj < 16; ++jj) {
      float v = hs[r][g * 16 + jj];
      vals[jj] = v; s1 += v; s2 += v * v;
    }
#pragma unroll
    for (int m = 1; m < 16; m <<= 1) { s1 += __shfl_xor(s1, m, 64); s2 += __shfl_xor(s2, m, 64); }
    const float mean = s1 * (1.f / 256.f);
    float var = fmaxf(s2 * (1.f / 256.f) - mean * mean, 0.f);
    const float rstd = rsqrtf(var + 1e-12f);
    f16 ov[16];
#pragma unroll
    for (int jj = 0; jj < 16; ++jj) {
      int kch = g * 16 + jj;
      float v = (vals[jj] - mean) * rstd * g3[kch] + bt3[kch];
      ov[jj] = (f16)gelu_exact(v);
    }
    *(f16x8*)(ts + r * 512 + ((g * 32) ^ ((r & 7) << 4))) = *(f16x8*)&ov[0];
    *(f16x8*)(ts + r * 512 + ((g * 32 + 16) ^ ((r & 7) << 4))) = *(f16x8*)&ov[8];
  }
  __syncthreads();
  if (w < 2) {
    const int n4 = w;
    f32x4 a4 = ZERO4;
#pragma unroll
    for (int ks = 0; ks < 8; ++ks) {
      f16x8 a = *(const f16x8*)(ts + mrow * 512 + (((ks << 6) + (kg << 4)) ^ ((mrow & 7) << 4)));
      int br = n4 * 16 + mrow;
      f16x8 bb = *(const f16x8*)(w4T + br * 256 + ks * 32 + kg * 8);
      a4 = __builtin_amdgcn_mfma_f32_16x16x32_f16(a, bb, a4, 0, 0, 0);
    }
    const int col = n4 * 16 + mrow;
#pragma unroll
    for (int i = 0; i < 4; ++i) {
      const int row = kg * 4 + i;
      const int l = l0 + row;
      float adj = tanhf(a4[i] + b4[col]) * 0.02f;
      float padj = __shfl_xor(adj, 1, 64);
      if ((lane & 1) == 0) {
        const int n = col >> 1;
        const float2 offv = *(const float2*)(offset + (((b << 9) + l) << 5) + col);
        const float pos0v = tanhf(offv.x + adj);
        const float ref_y = ((float)n + 0.5f) * ((float)l + 1e-9f) * (1.0f / 4096.0f) - 1.0f;
        const float pos1v = tanhf(offv.y + padj + ref_y);
        *(float2*)(off_out + (((b << 9) + l) << 5) + col) = offv;
        *(float2*)(pos_out + (((b << 9) + l) << 5) + col) = make_float2(pos0v, pos1v);
      }
    }
  }
}

// ---------------------------------------------------------------- K4 (XCD-local, NT — R12 exact)
__global__ __launch_bounds__(256) void k4_gather(
    const float* __restrict__ x, const float* __restrict__ pos,
    float* __restrict__ outbuf) {
  const int blk = blockIdx.x;
  const int b = ((blk & 7) << 2) | ((blk >> 3) & 3);
  const int grp = blk >> 5;
  const int w = threadIdx.x >> 6, lane = threadIdx.x & 63;
  const int p0 = (grp << 5) + (w << 3);
  const unsigned tbase = ((unsigned)b << 13) + (unsigned)p0;
  const f32x4* xb = (const f32x4*)x + ((unsigned)(b << 9)) * 64u + lane;
  f32x4* ob = (f32x4*)outbuf + (unsigned)tbase * 64u + lane;

  float pw[8];
#pragma unroll
  for (int i = 0; i < 8; ++i) pw[i] = pos[(tbase + i) * 2 + 1];

  int cc0[8], cc1[8];
  float w0v[8], w1v[8];
#pragma unroll
  for (int i = 0; i < 8; ++i) {
    const int l = (p0 + i) >> 4;
    const float pix = (pw[i] + 1.0f) * 0.5f * 511.0f;
    const float i0f = floorf(pix);
    const int i0 = (int)i0f;
    const float frac = pix - i0f;
    const int i1 = i0 + 1;
    const bool v0 = (i0 >= 0) && (i0 < 512) && (i0 <= l);
    const bool v1 = (i1 >= 0) && (i1 < 512) && (i1 <= l);
    cc0[i] = i0 < 0 ? 0 : (i0 > 511 ? 511 : i0);
    cc1[i] = i1 < 0 ? 0 : (i1 > 511 ? 511 : i1);
    w0v[i] = v0 ? (1.0f - frac) : 0.0f;
    w1v[i] = v1 ? frac : 0.0f;
  }

#pragma unroll
  for (int g = 0; g < 2; ++g) {
    f32x4 va[4], vb[4];
#pragma unroll
    for (int j = 0; j < 4; ++j) {
      va[j] = xb[(unsigned)cc0[g * 4 + j] * 64u];
      vb[j] = xb[(unsigned)cc1[g * 4 + j] * 64u];
    }
#pragma unroll
    for (int j = 0; j < 4; ++j) {
      f32x4 o = w0v[g * 4 + j] * va[j] + w1v[g * 4 + j] * vb[j];
      __builtin_nontemporal_store(o, ob + (unsigned)(g * 4 + j) * 64u);
    }
  }
}

extern "C" void kernel_launch(void* const* d_in, const int* in_sizes, int n_in,
                              void* d_out, int out_size, void* d_ws, size_t ws_size,
                              hipStream_t stream) {
  const float* query  = (const float*)d_in[0];
  const float* x      = (const float*)d_in[1];
  const float* offset = (const float*)d_in[2];
  const float* w1  = (const float*)d_in[3];
  const float* b1  = (const float*)d_in[4];
  const float* g1  = (const float*)d_in[5];
  const float* bt1 = (const float*)d_in[6];
  const float* w2  = (const float*)d_in[7];
  const float* b2  = (const float*)d_in[8];
  const float* w3  = (const float*)d_in[9];
  const float* b3  = (const float*)d_in[10];
  const float* g3  = (const float*)d_in[11];
  const float* bt3 = (const float*)d_in[12];
  const float* w4  = (const float*)d_in[13];
  const float* b4  = (const float*)d_in[14];

  float* out     = (float*)d_out;                    // [B,L,N,C]
  float* off_out = out + 67108864;                   // [B,L,2N]
  float* pos_out = off_out + 524288;                 // [B,L,N,2]

  f16* w1T = (f16*)d_ws;                             // [128][512]
  f16* w2T = w1T + 65536;                            // [512][128]
  f16* w3T = w2T + 65536;                            // [256][256]
  f16* w4T = w3T + 65536;                            // [32][256]
  f16* q   = w4T + 8192;                             // [32][512][256]

  k0_prep<<<52, 256, 0, stream>>>(w1, w2, w3, w4, w1T, w2T, w3T, w4T);
  k12_sample<<<512, 256, 0, stream>>>(query, w1T, w2T, b1, g1, bt1, b2, q);
  k3_adjust<<<1024, 256, 0, stream>>>(q, w3T, b3, g3, bt3, w4T, b4, offset,
                                      off_out, pos_out);
  k4_gather<<<8192, 256, 0, stream>>>(x, pos_out, out);
}

// Round 21
// 102.316 us; speedup vs baseline: 1.0305x; 1.0305x over previous
//
#include <hip/hip_runtime.h>
#include <hip/hip_fp16.h>
#include <math.h>

// AdjustNet: B=32, L=512, C=256, N=16 — FINAL: R17/R19 validated best (~103.4us).
// R20's K3 A-direct regressed (+1.7us: per-k-step global A-loads put L2 latency
// on the MFMA critical path) — reverted. Lesson: destage only loop-INVARIANT
// L2-resident operands (R17's w4t/sb3), keep streamed tiles in LDS.
//  K0: transpose+cast weights
//  K12: fused sample_layer (GEMM1+LN+GELU in LDS, GEMM2), BK=64, reg-prefetched
//  K3: adjust_layer, 34.8KB LDS -> 4 blocks/CU, w4T/b3 direct from L2
//  K4: gather-blend, XCD-local batches (b fixed per XCD slot), batched-ILP
//      loads, NT stores (A/B-proven vs plain both directions)

typedef _Float16 f16;
typedef _Float16 f16x8 __attribute__((ext_vector_type(8)));
typedef float f32x4 __attribute__((ext_vector_type(4)));

#define ZERO4 f32x4{0.f, 0.f, 0.f, 0.f}

__device__ __forceinline__ float gelu_exact(float v) {
  return 0.5f * v * (1.0f + erff(v * 0.70710678118654752f));
}

// ---------------------------------------------------------------- K0 (weights only)
__global__ __launch_bounds__(256) void k0_prep(
    const float* __restrict__ w1, const float* __restrict__ w2,
    const float* __restrict__ w3, const float* __restrict__ w4,
    f16* __restrict__ w1T, f16* __restrict__ w2T,
    f16* __restrict__ w3T, f16* __restrict__ w4T) {
  __shared__ f16 tile[64][80];
  int blk = blockIdx.x;
  const int tid = threadIdx.x;
  const float* in; f16* out; int R, Cc, tr, tc;
  if (blk < 16)      { in = w1; out = w1T; R = 512; Cc = 128; tr = blk >> 1; tc = blk & 1; }
  else if (blk < 32) { blk -= 16; in = w2; out = w2T; R = 128; Cc = 512; tr = blk >> 3; tc = blk & 7; }
  else if (blk < 48) { blk -= 32; in = w3; out = w3T; R = 256; Cc = 256; tr = blk >> 2; tc = blk & 3; }
  else               { blk -= 48; in = w4; out = w4T; R = 256; Cc = 32;  tr = blk;      tc = 0; }
  const int r0 = tr * 64, c0 = tc * 64;
  for (int id = tid; id < 4096; id += 256) {
    int rr = id >> 6, cc = id & 63;
    if (c0 + cc < Cc) tile[cc][rr] = (f16)in[(r0 + rr) * Cc + c0 + cc];
  }
  __syncthreads();
  for (int id = tid; id < 512; id += 256) {
    int cc = id >> 3, ch = id & 7;
    if (c0 + cc < Cc)
      *(f16x8*)(out + (c0 + cc) * R + r0 + ch * 8) = *(f16x8*)&tile[cc][ch * 8];
  }
}

// ---------------------------------------------------------------- K12
// grid 512: b = blk>>4, c0 = (blk&15)*16.
__global__ __launch_bounds__(256) void k12_sample(
    const float* __restrict__ query, const f16* __restrict__ w1T,
    const f16* __restrict__ w2T,
    const float* __restrict__ b1, const float* __restrict__ g1,
    const float* __restrict__ bt1, const float* __restrict__ b2,
    f16* __restrict__ qout) {
  __shared__ char pool[38912];
  const int tid = threadIdx.x;
  const int b = blockIdx.x >> 4;
  const int c0 = (blockIdx.x & 15) << 4;
  const int lane = tid & 63, w = tid >> 6;
  const int mrow = lane & 15, kg = lane >> 4;
  char* At = pool;
  char* Bt = pool + 2048;
  char* t1s = pool + 32768;
  float* sb2 = (float*)(pool + 36864);

  sb2[tid] = b2[tid];
  sb2[tid + 256] = b2[tid + 256];

  const int qll = tid >> 4, qcc = tid & 15;
  const int wrj = tid >> 3, wch = tid & 7;
  float qv[4]; f16x8 wv[4];
#pragma unroll
  for (int it = 0; it < 4; ++it) {
    qv[it] = query[(((b << 9) + qll + it * 16) << 8) + c0 + qcc];
    wv[it] = *(const f16x8*)(w1T + (wrj + it * 32) * 512 + wch * 8);
  }

  f32x4 acc[2] = {ZERO4, ZERO4};
  for (int s = 0; s < 8; ++s) {
#pragma unroll
    for (int it = 0; it < 4; ++it) {
      int ll = qll + it * 16;
      *(f16*)(At + qcc * 128 + ((2 * ll) ^ ((qcc & 7) << 4))) = (f16)qv[it];
    }
#pragma unroll
    for (int it = 0; it < 4; ++it) {
      int rj = wrj + it * 32;
      *(f16x8*)(Bt + rj * 128 + ((wch * 16) ^ ((rj & 7) << 4))) = wv[it];
    }
    __syncthreads();
    if (s < 7) {
      const int k0n = (s + 1) << 6;
#pragma unroll
      for (int it = 0; it < 4; ++it) {
        qv[it] = query[(((b << 9) + k0n + qll + it * 16) << 8) + c0 + qcc];
        wv[it] = *(const f16x8*)(w1T + (wrj + it * 32) * 512 + k0n + wch * 8);
      }
    }
#pragma unroll
    for (int kk = 0; kk < 2; ++kk) {
      f16x8 a = *(const f16x8*)(At + mrow * 128 + (((kk << 6) + (kg << 4)) ^ ((mrow & 7) << 4)));
#pragma unroll
      for (int nf = 0; nf < 2; ++nf) {
        int rn = w * 32 + nf * 16 + mrow;
        f16x8 bfr = *(const f16x8*)(Bt + rn * 128 + (((kk << 6) + (kg << 4)) ^ ((rn & 7) << 4)));
        acc[nf] = __builtin_amdgcn_mfma_f32_16x16x32_f16(a, bfr, acc[nf], 0, 0, 0);
      }
    }
    __syncthreads();
  }

  f16x8 av[8];
#pragma unroll
  for (int it = 0; it < 8; ++it)
    av[it] = *(const f16x8*)(w2T + ((tid >> 4) + it * 16) * 128 + (tid & 15) * 8);

  float (*hs)[132] = (float(*)[132])pool;
#pragma unroll
  for (int nf = 0; nf < 2; ++nf)
#pragma unroll
    for (int i = 0; i < 4; ++i)
      hs[kg * 4 + i][w * 32 + nf * 16 + mrow] = acc[nf][i];
  __syncthreads();
  {
    const int r = tid >> 4, g = tid & 15;
    float s1 = 0.f, s2 = 0.f, vals[8];
#pragma unroll
    for (int jj = 0; jj < 8; ++jj) {
      int j = g * 8 + jj;
      float v = hs[r][j] + b1[j];
      vals[jj] = v; s1 += v; s2 += v * v;
    }
#pragma unroll
    for (int m = 1; m < 16; m <<= 1) { s1 += __shfl_xor(s1, m, 64); s2 += __shfl_xor(s2, m, 64); }
    const float mean = s1 * (1.f / 128.f);
    float var = fmaxf(s2 * (1.f / 128.f) - mean * mean, 0.f);
    const float rstd = rsqrtf(var + 1e-12f);
    f16 ov[8];
#pragma unroll
    for (int jj = 0; jj < 8; ++jj) {
      int j = g * 8 + jj;
      float v = (vals[jj] - mean) * rstd * g1[j] + bt1[j];
      ov[jj] = (f16)gelu_exact(v);
    }
    __syncthreads();
    *(f16x8*)(t1s + r * 256 + ((g * 16) ^ ((r & 7) << 4))) = *(f16x8*)ov;
  }
  __syncthreads();

  char* At2 = pool;
  const int ar2 = tid >> 4, ac2 = tid & 15;
  for (int lc = 0; lc < 4; ++lc) {
#pragma unroll
    for (int it = 0; it < 8; ++it) {
      int r = ar2 + it * 16;
      *(f16x8*)(At2 + r * 256 + ((ac2 * 16) ^ ((r & 7) << 4))) = av[it];
    }
    __syncthreads();
    if (lc < 3) {
#pragma unroll
      for (int it = 0; it < 8; ++it)
        av[it] = *(const f16x8*)(w2T + ((lc + 1) * 128 + ar2 + it * 16) * 128 + ac2 * 8);
    }
    f32x4 acc2[2] = {ZERO4, ZERO4};
#pragma unroll
    for (int ks = 0; ks < 4; ++ks) {
      f16x8 bfr = *(const f16x8*)(t1s + mrow * 256 + (((ks << 6) + (kg << 4)) ^ ((mrow & 7) << 4)));
#pragma unroll
      for (int mf = 0; mf < 2; ++mf) {
        int rm = w * 32 + mf * 16 + mrow;
        f16x8 a = *(const f16x8*)(At2 + rm * 256 + (((ks << 6) + (kg << 4)) ^ ((rm & 7) << 4)));
        acc2[mf] = __builtin_amdgcn_mfma_f32_16x16x32_f16(a, bfr, acc2[mf], 0, 0, 0);
      }
    }
#pragma unroll
    for (int mf = 0; mf < 2; ++mf)
#pragma unroll
      for (int i = 0; i < 4; ++i) {
        int l = lc * 128 + w * 32 + mf * 16 + kg * 4 + i;
        qout[((b << 9) + l) * 256 + c0 + mrow] = (f16)(acc2[mf][i] + sb2[l]);
      }
    __syncthreads();
  }
}

// ---------------------------------------------------------------- K3 (34.8KB LDS, 4 blocks/CU)
// grid 1024: b=blk>>5, l0=(blk&31)*16. w4T/b3 read direct from L2 (no staging).
__global__ __launch_bounds__(256) void k3_adjust(
    const f16* __restrict__ qbuf, const f16* __restrict__ w3T,
    const float* __restrict__ b3, const float* __restrict__ g3,
    const float* __restrict__ bt3, const f16* __restrict__ w4T,
    const float* __restrict__ b4, const float* __restrict__ offset,
    float* __restrict__ off_out, float* __restrict__ pos_out) {
  __shared__ __align__(16) char pool[34816];
  const int tid = threadIdx.x;
  const int b = blockIdx.x >> 5;
  const int l0 = (blockIdx.x & 31) << 4;
  const int lane = tid & 63, w = tid >> 6;
  const int mrow = lane & 15, kg = lane >> 4;
  char* At = pool;
  char* Bt = pool + 2048;

  const int sr = tid >> 3, sc = tid & 7;
  f16x8 aq; f16x8 bq[8];
  if (tid < 128) aq = *(const f16x8*)(qbuf + ((b << 9) + l0 + sr) * 256 + sc * 8);
#pragma unroll
  for (int it = 0; it < 8; ++it)
    bq[it] = *(const f16x8*)(w3T + (sr + it * 32) * 256 + sc * 8);

  f32x4 acc[4] = {ZERO4, ZERO4, ZERO4, ZERO4};
  for (int s = 0; s < 4; ++s) {
    if (tid < 128)
      *(f16x8*)(At + sr * 128 + ((sc * 16) ^ ((sr & 7) << 4))) = aq;
#pragma unroll
    for (int it = 0; it < 8; ++it) {
      int r = sr + it * 32;
      *(f16x8*)(Bt + r * 128 + ((sc * 16) ^ ((r & 7) << 4))) = bq[it];
    }
    __syncthreads();
    if (s < 3) {
      const int k0n = (s + 1) << 6;
      if (tid < 128) aq = *(const f16x8*)(qbuf + ((b << 9) + l0 + sr) * 256 + k0n + sc * 8);
#pragma unroll
      for (int it = 0; it < 8; ++it)
        bq[it] = *(const f16x8*)(w3T + (sr + it * 32) * 256 + k0n + sc * 8);
    }
#pragma unroll
    for (int kk = 0; kk < 2; ++kk) {
      f16x8 a = *(const f16x8*)(At + mrow * 128 + (((kk << 6) + (kg << 4)) ^ ((mrow & 7) << 4)));
#pragma unroll
      for (int nf = 0; nf < 4; ++nf) {
        int rn = w * 64 + nf * 16 + mrow;
        f16x8 bfr = *(const f16x8*)(Bt + rn * 128 + (((kk << 6) + (kg << 4)) ^ ((rn & 7) << 4)));
        acc[nf] = __builtin_amdgcn_mfma_f32_16x16x32_f16(a, bfr, acc[nf], 0, 0, 0);
      }
    }
    __syncthreads();
  }
  float (*hs)[264] = (float(*)[264])pool;
  char* ts = pool + 17408;
#pragma unroll
  for (int nf = 0; nf < 4; ++nf) {
    int col = w * 64 + nf * 16 + mrow;
    float bias = b3[col];
#pragma unroll
    for (int i = 0; i < 4; ++i)
      hs[kg * 4 + i][col] = acc[nf][i] + bias;
  }
  __syncthreads();
  {
    const int r = tid >> 4, g = tid & 15;
    float s1 = 0.f, s2 = 0.f, vals[16];
#pragma unroll
    for (int jj = 0; jj < 16; ++jj) {
      float v = hs[r][g * 16 + jj];
      vals[jj] = v; s1 += v; s2 += v * v;
    }
#pragma unroll
    for (int m = 1; m < 16; m <<= 1) { s1 += __shfl_xor(s1, m, 64); s2 += __shfl_xor(s2, m, 64); }
    const float mean = s1 * (1.f / 256.f);
    float var = fmaxf(s2 * (1.f / 256.f) - mean * mean, 0.f);
    const float rstd = rsqrtf(var + 1e-12f);
    f16 ov[16];
#pragma unroll
    for (int jj = 0; jj < 16; ++jj) {
      int kch = g * 16 + jj;
      float v = (vals[jj] - mean) * rstd * g3[kch] + bt3[kch];
      ov[jj] = (f16)gelu_exact(v);
    }
    *(f16x8*)(ts + r * 512 + ((g * 32) ^ ((r & 7) << 4))) = *(f16x8*)&ov[0];
    *(f16x8*)(ts + r * 512 + ((g * 32 + 16) ^ ((r & 7) << 4))) = *(f16x8*)&ov[8];
  }
  __syncthreads();
  if (w < 2) {
    const int n4 = w;
    f32x4 a4 = ZERO4;
#pragma unroll
    for (int ks = 0; ks < 8; ++ks) {
      f16x8 a = *(const f16x8*)(ts + mrow * 512 + (((ks << 6) + (kg << 4)) ^ ((mrow & 7) << 4)));
      int br = n4 * 16 + mrow;
      f16x8 bb = *(const f16x8*)(w4T + br * 256 + ks * 32 + kg * 8);
      a4 = __builtin_amdgcn_mfma_f32_16x16x32_f16(a, bb, a4, 0, 0, 0);
    }
    const int col = n4 * 16 + mrow;
#pragma unroll
    for (int i = 0; i < 4; ++i) {
      const int row = kg * 4 + i;
      const int l = l0 + row;
      float adj = tanhf(a4[i] + b4[col]) * 0.02f;
      float padj = __shfl_xor(adj, 1, 64);
      if ((lane & 1) == 0) {
        const int n = col >> 1;
        const float2 offv = *(const float2*)(offset + (((b << 9) + l) << 5) + col);
        const float pos0v = tanhf(offv.x + adj);
        const float ref_y = ((float)n + 0.5f) * ((float)l + 1e-9f) * (1.0f / 4096.0f) - 1.0f;
        const float pos1v = tanhf(offv.y + padj + ref_y);
        *(float2*)(off_out + (((b << 9) + l) << 5) + col) = offv;
        *(float2*)(pos_out + (((b << 9) + l) << 5) + col) = make_float2(pos0v, pos1v);
      }
    }
  }
}

// ---------------------------------------------------------------- K4 (XCD-local, NT — R12 exact)
__global__ __launch_bounds__(256) void k4_gather(
    const float* __restrict__ x, const float* __restrict__ pos,
    float* __restrict__ outbuf) {
  const int blk = blockIdx.x;
  const int b = ((blk & 7) << 2) | ((blk >> 3) & 3);
  const int grp = blk >> 5;
  const int w = threadIdx.x >> 6, lane = threadIdx.x & 63;
  const int p0 = (grp << 5) + (w << 3);
  const unsigned tbase = ((unsigned)b << 13) + (unsigned)p0;
  const f32x4* xb = (const f32x4*)x + ((unsigned)(b << 9)) * 64u + lane;
  f32x4* ob = (f32x4*)outbuf + (unsigned)tbase * 64u + lane;

  float pw[8];
#pragma unroll
  for (int i = 0; i < 8; ++i) pw[i] = pos[(tbase + i) * 2 + 1];

  int cc0[8], cc1[8];
  float w0v[8], w1v[8];
#pragma unroll
  for (int i = 0; i < 8; ++i) {
    const int l = (p0 + i) >> 4;
    const float pix = (pw[i] + 1.0f) * 0.5f * 511.0f;
    const float i0f = floorf(pix);
    const int i0 = (int)i0f;
    const float frac = pix - i0f;
    const int i1 = i0 + 1;
    const bool v0 = (i0 >= 0) && (i0 < 512) && (i0 <= l);
    const bool v1 = (i1 >= 0) && (i1 < 512) && (i1 <= l);
    cc0[i] = i0 < 0 ? 0 : (i0 > 511 ? 511 : i0);
    cc1[i] = i1 < 0 ? 0 : (i1 > 511 ? 511 : i1);
    w0v[i] = v0 ? (1.0f - frac) : 0.0f;
    w1v[i] = v1 ? frac : 0.0f;
  }

#pragma unroll
  for (int g = 0; g < 2; ++g) {
    f32x4 va[4], vb[4];
#pragma unroll
    for (int j = 0; j < 4; ++j) {
      va[j] = xb[(unsigned)cc0[g * 4 + j] * 64u];
      vb[j] = xb[(unsigned)cc1[g * 4 + j] * 64u];
    }
#pragma unroll
    for (int j = 0; j < 4; ++j) {
      f32x4 o = w0v[g * 4 + j] * va[j] + w1v[g * 4 + j] * vb[j];
      __builtin_nontemporal_store(o, ob + (unsigned)(g * 4 + j) * 64u);
    }
  }
}

extern "C" void kernel_launch(void* const* d_in, const int* in_sizes, int n_in,
                              void* d_out, int out_size, void* d_ws, size_t ws_size,
                              hipStream_t stream) {
  const float* query  = (const float*)d_in[0];
  const float* x      = (const float*)d_in[1];
  const float* offset = (const float*)d_in[2];
  const float* w1  = (const float*)d_in[3];
  const float* b1  = (const float*)d_in[4];
  const float* g1  = (const float*)d_in[5];
  const float* bt1 = (const float*)d_in[6];
  const float* w2  = (const float*)d_in[7];
  const float* b2  = (const float*)d_in[8];
  const float* w3  = (const float*)d_in[9];
  const float* b3  = (const float*)d_in[10];
  const float* g3  = (const float*)d_in[11];
  const float* bt3 = (const float*)d_in[12];
  const float* w4  = (const float*)d_in[13];
  const float* b4  = (const float*)d_in[14];

  float* out     = (float*)d_out;                    // [B,L,N,C]
  float* off_out = out + 67108864;                   // [B,L,2N]
  float* pos_out = off_out + 524288;                 // [B,L,N,2]

  f16* w1T = (f16*)d_ws;                             // [128][512]
  f16* w2T = w1T + 65536;                            // [512][128]
  f16* w3T = w2T + 65536;                            // [256][256]
  f16* w4T = w3T + 65536;                            // [32][256]
  f16* q   = w4T + 8192;                             // [32][512][256]

  k0_prep<<<52, 256, 0, stream>>>(w1, w2, w3, w4, w1T, w2T, w3T, w4T);
  k12_sample<<<512, 256, 0, stream>>>(query, w1T, w2T, b1, g1, bt1, b2, q);
  k3_adjust<<<1024, 256, 0, stream>>>(q, w3T, b3, g3, bt3, w4T, b4, offset,
                                      off_out, pos_out);
  k4_gather<<<8192, 256, 0, stream>>>(x, pos_out, out);
}